// Round 5
// baseline (757.086 us; speedup 1.0000x reference)
//
#include <hip/hip_runtime.h>
#include <math.h>

#define SC 4
#define BB 2
#define CC 32
#define HH 256
#define WW 512
#define CH (HH / SC)   // 64
#define CW (WW / SC)   // 128

// Direction metadata (output channel order: c, l, r, t, b, lt, rt, lb, rb)
// dh/dw: coarse-cell (and /4 pixel) offsets. s0/s1: distance-channel selector.
//   s0: 0 -> xv (x[w%4]), 1 -> 4-(w%4) (D1), 2 -> (w%4)+1 (D2)
//   s1: 0 -> yv (x[h%4]), 1 -> 4-(h%4) (D3), 2 -> (h%4)+1 (D4)
// Diagonals reuse D1..D4 which modify ONLY ONE channel each:
//   lt->D1 (ch0=x1, ch1=yv), rt->D2 (ch0=x2, ch1=yv),
//   lb->D3 (ch0=xv, ch1=y1), rb->D4 (ch0=xv, ch1=y2).   [verified R2]
__device__ __constant__ int c_dh[9] = {0, 0, 0, -1, 1, -1, -1, 1, 1};
__device__ __constant__ int c_dw[9] = {0, -1, 1, 0, 0, -1, 1, -1, 1};
__device__ __constant__ int c_s0[9] = {0, 1, 2, 0, 0, 1, 2, 0, 0};
__device__ __constant__ int c_s1[9] = {0, 0, 0, 1, 2, 0, 0, 1, 2};

// Pre-pass: ALr[(b*CH+cy)*CW+cx][o] = sum_c w0[o*66+c] * lr[b][c][cy][cx]
__global__ __launch_bounds__(256)
__attribute__((amdgpu_waves_per_eu(4, 4)))
void alr_prepass(const float* __restrict__ lr,
                 const float* __restrict__ w0,
                 float* __restrict__ alr) {
    const int idx = blockIdx.x * 256 + threadIdx.x;  // over BB*CH*CW = 16384
    if (idx >= BB * CH * CW) return;
    const int b = idx / (CH * CW);
    const int cell = idx - b * (CH * CW);
    const float* lp = lr + (size_t)b * CC * CH * CW + cell;
    float acc[32];
#pragma unroll
    for (int o = 0; o < 32; o++) acc[o] = 0.f;
#pragma unroll
    for (int c = 0; c < 32; c++) {
        const float lv = lp[(size_t)c * (CH * CW)];
#pragma unroll
        for (int o = 0; o < 32; o++) acc[o] = fmaf(lv, w0[o * 66 + c], acc[o]);
    }
    float4* op = (float4*)(alr + (size_t)idx * 32);
#pragma unroll
    for (int j = 0; j < 8; j++)
        op[j] = make_float4(acc[4 * j], acc[4 * j + 1], acc[4 * j + 2], acc[4 * j + 3]);
}

// Main: one thread per hr pixel; block covers a 4(h) x 64(w) tile.
//
// Occupancy note (R4 post-mortem): the grid is 1024 blocks = 4 blocks/CU =
// 4 waves/EU MAX from dispatch. __launch_bounds__(256,4) only sets the waves
// MIN, so the scheduler still targeted 8-10 waves/EU, budgeted 48-56 VGPRs,
// and spill-churned the ~70-reg live set (15x VALU inflation, 511us).
// amdgpu_waves_per_eu(4,4) pins the target = grid capacity -> 128-VGPR
// budget -> no spills.
template <bool USE_WS>
__global__ __launch_bounds__(256)
__attribute__((amdgpu_waves_per_eu(4, 4)))
void ercm_main(const float* __restrict__ hr,
               const float* __restrict__ lr,
               const float* __restrict__ alr,
               const float* __restrict__ w0,
               const float* __restrict__ w1,
               const float* __restrict__ w2,
               const float* __restrict__ w3,
               float* __restrict__ out) {
    // 3 coarse rows x 18 coarse cols of 32-float ALr vectors, padded to 36
    // floats/cell (stride-32 would be a 16-way bank conflict on ds_read_b128;
    // 36 rotates 4 banks/cell -> 2-way broadcast groups, which is free).
    __shared__ float s_alr[54 * 36];
    __shared__ float s_lg[9 * 256];  // per-direction logits (rolled d-loop;
                                     // LDS avoids dynamic-index scratch demotion)

    const int tid = threadIdx.x;
    const int bx = blockIdx.x;  // 0..7   (WW/64)
    const int by = blockIdx.y;  // 0..63  (HH/4)
    const int b = blockIdx.z;   // 0..1
    const int cy0 = by, cx0 = bx * 16;

    if (USE_WS) {
        for (int i = tid; i < 54 * 32; i += 256) {
            const int c = i & 31, cell = i >> 5;
            const int row = cell / 18, col = cell - row * 18;
            const int gcy = cy0 - 1 + row, gcx = cx0 - 1 + col;
            float v = 0.f;
            if ((unsigned)gcy < (unsigned)CH && (unsigned)gcx < (unsigned)CW)
                v = alr[(((size_t)b * CH + gcy) * CW + gcx) * 32 + c];
            s_alr[cell * 36 + c] = v;
        }
    } else {
        // Fallback if workspace too small: compute ALr tile in-block.
        for (int i = tid; i < 54 * 32; i += 256) {
            const int o = i & 31, cell = i >> 5;
            const int row = cell / 18, col = cell - row * 18;
            const int gcy = cy0 - 1 + row, gcx = cx0 - 1 + col;
            float a = 0.f;
            if ((unsigned)gcy < (unsigned)CH && (unsigned)gcx < (unsigned)CW) {
                const float* lp = lr + (size_t)b * CC * CH * CW + (size_t)gcy * CW + gcx;
#pragma unroll
                for (int c = 0; c < 32; c++) a = fmaf(lp[(size_t)c * (CH * CW)], w0[o * 66 + c], a);
            }
            s_alr[cell * 36 + o] = a;
        }
    }
    __syncthreads();

    const int tx = tid & 63, ty = tid >> 6;
    const int h = by * 4 + ty, w = bx * 64 + tx;
    const size_t HW = (size_t)HH * WW;

    // A_hr[o] = sum_c hr[c] * w0[o, 32+c] -- dual orientation: stream hr
    // channels, 32 independent FMA chains, no hrv[] array.
    float ahr[32];
#pragma unroll
    for (int o = 0; o < 32; o++) ahr[o] = 0.f;
    const float* hp = hr + (size_t)b * CC * HW + (size_t)h * WW + w;
#pragma unroll
    for (int c = 0; c < 32; c++) {
        const float hv = hp[(size_t)c * HW];
#pragma unroll
        for (int o = 0; o < 32; o++) ahr[o] = fmaf(hv, w0[o * 66 + 32 + c], ahr[o]);
    }

    const int xm = w & 3, ym = h & 3;
    const float xv = (float)(xm < 2 ? xm - 2 : xm - 1);  // x = [-2,-1,1,2]
    const float yv = (float)(ym < 2 ? ym - 2 : ym - 1);
    const float x1 = (float)(4 - xm), x2 = (float)(xm + 1);
    const float y1 = (float)(4 - ym), y2 = (float)(ym + 1);
    const int baseCell = (tx >> 2) + 1;  // local coarse col (+1 halo offset)

#pragma unroll 1  // keep rolled: 9x unroll would blow I-cache
    for (int d = 0; d < 9; d++) {
        const int dh = c_dh[d], dw = c_dw[d];
        const int sel0 = c_s0[d], sel1 = c_s1[d];
        const float d0 = (sel0 == 0) ? xv : ((sel0 == 1) ? x1 : x2);
        const float d1 = (sel1 == 0) ? yv : ((sel1 == 1) ? y1 : y2);
        const bool valid = ((unsigned)(h + 4 * dh) < (unsigned)HH) &&
                           ((unsigned)(w + 4 * dw) < (unsigned)WW);

        const float4* ap4 = (const float4*)(s_alr + ((1 + dh) * 18 + baseCell + dw) * 36);

        // Fused layer1 -> layer2 (dual): per layer-1 output o, compute
        // t = leaky(ahr[o] + alr[o] + dist) and scatter into 16 layer-2
        // accumulators (independent chains). Accumulation order over o
        // matches the reference's order over c -> numerics identical.
        float acc2[16];
#pragma unroll
        for (int j = 0; j < 16; j++) acc2[j] = 0.f;
#pragma unroll
        for (int jq = 0; jq < 8; jq++) {
            const float4 q = ap4[jq];
#pragma unroll
            for (int k = 0; k < 4; k++) {
                const int o = 4 * jq + k;
                const float av = (k == 0) ? q.x : (k == 1) ? q.y : (k == 2) ? q.z : q.w;
                float t = ahr[o] + av;
                t = fmaf(d0, w0[o * 66 + 64], t);
                t = fmaf(d1, w0[o * 66 + 65], t);
                t = fmaxf(t, 0.01f * t);
#pragma unroll
                for (int j = 0; j < 16; j++) acc2[j] = fmaf(t, w1[j * 32 + o], acc2[j]);
            }
        }
        // layer 3: 16 -> 8 (leaky applied to layer-2 accs on the fly)
        float h2[8];
#pragma unroll
        for (int o = 0; o < 8; o++) h2[o] = 0.f;
#pragma unroll
        for (int c = 0; c < 16; c++) {
            const float t = fmaxf(acc2[c], 0.01f * acc2[c]);
#pragma unroll
            for (int o = 0; o < 8; o++) h2[o] = fmaf(t, w2[o * 16 + c], h2[o]);
        }
        // layer 4: 8 -> 1 (leaky on h2, then dot with w3)
        float lg = 0.f;
#pragma unroll
        for (int c = 0; c < 8; c++) {
            const float t = fmaxf(h2[c], 0.01f * h2[c]);
            lg = fmaf(t, w3[c], lg);
        }

        s_lg[d * 256 + tid] = valid ? lg : -100.0f;
    }

    // softmax over the 9 direction logits
    float l[9];
#pragma unroll
    for (int d = 0; d < 9; d++) l[d] = s_lg[d * 256 + tid];
    float m = l[0];
#pragma unroll
    for (int d = 1; d < 9; d++) m = fmaxf(m, l[d]);
    float s = 0.f;
#pragma unroll
    for (int d = 0; d < 9; d++) {
        l[d] = __expf(l[d] - m);
        s += l[d];
    }
    const float inv = __builtin_amdgcn_rcpf(s);
    float* op = out + (size_t)b * 9 * HW + (size_t)h * WW + w;
#pragma unroll
    for (int d = 0; d < 9; d++) op[(size_t)d * HW] = l[d] * inv;
}

extern "C" void kernel_launch(void* const* d_in, const int* in_sizes, int n_in,
                              void* d_out, int out_size, void* d_ws, size_t ws_size,
                              hipStream_t stream) {
    const float* lr = (const float*)d_in[0];
    const float* hr = (const float*)d_in[1];
    // d_in[2], d_in[3] (lr_feature_r / hr_feature_r) are unused by the reference.
    const float* w0 = (const float*)d_in[4];
    const float* w1 = (const float*)d_in[5];
    const float* w2 = (const float*)d_in[6];
    const float* w3 = (const float*)d_in[7];
    float* out = (float*)d_out;

    const size_t alr_bytes = (size_t)BB * CH * CW * 32 * sizeof(float);  // 2 MB
    dim3 grid(WW / 64, HH / 4, BB);  // 8 x 64 x 2 = 1024 blocks

    if (ws_size >= alr_bytes) {
        float* alr = (float*)d_ws;
        alr_prepass<<<(BB * CH * CW + 255) / 256, 256, 0, stream>>>(lr, w0, alr);
        ercm_main<true><<<grid, 256, 0, stream>>>(hr, lr, alr, w0, w1, w2, w3, out);
    } else {
        ercm_main<false><<<grid, 256, 0, stream>>>(hr, lr, nullptr, w0, w1, w2, w3, out);
    }
}

// Round 6
// 635.590 us; speedup vs baseline: 1.1912x; 1.1912x over previous
//
#include <hip/hip_runtime.h>
#include <math.h>

#define SC 4
#define BB 2
#define CC 32
#define HH 256
#define WW 512
#define CH (HH / SC)   // 64
#define CW (WW / SC)   // 128

// Direction metadata (output channel order: c, l, r, t, b, lt, rt, lb, rb)
//   s0: 0 -> xv (x[w%4]), 1 -> 4-(w%4) (D1), 2 -> (w%4)+1 (D2)
//   s1: 0 -> yv (x[h%4]), 1 -> 4-(h%4) (D3), 2 -> (h%4)+1 (D4)
// Diagonals reuse D1..D4 which modify ONLY ONE channel each:
//   lt->D1 (ch0=x1, ch1=yv), rt->D2 (ch0=x2, ch1=yv),
//   lb->D3 (ch0=xv, ch1=y1), rb->D4 (ch0=xv, ch1=y2).   [verified R2]
__device__ __constant__ int c_dh[9] = {0, 0, 0, -1, 1, -1, -1, 1, 1};
__device__ __constant__ int c_dw[9] = {0, -1, 1, 0, 0, -1, 1, -1, 1};
__device__ __constant__ int c_s0[9] = {0, 1, 2, 0, 0, 1, 2, 0, 0};
__device__ __constant__ int c_s1[9] = {0, 0, 0, 1, 2, 0, 0, 1, 2};

// Pre-pass: ALr[(b*CH+cy)*CW+cx][o] = sum_c w0[o*66+c] * lr[b][c][cy][cx]
__global__ __launch_bounds__(256) void alr_prepass(const float* __restrict__ lr,
                                                   const float* __restrict__ w0,
                                                   float* __restrict__ alr) {
    const int idx = blockIdx.x * 256 + threadIdx.x;  // over BB*CH*CW = 16384
    if (idx >= BB * CH * CW) return;
    const int b = idx / (CH * CW);
    const int cell = idx - b * (CH * CW);
    const float* lp = lr + (size_t)b * CC * CH * CW + cell;
    float acc[32];
#pragma unroll
    for (int o = 0; o < 32; o++) acc[o] = 0.f;
    // c-chunked by 8: w0 row chunks are contiguous (s_load_dwordx8-able),
    // live set = acc[32] + lv[8] + ~10 scalars.
#pragma unroll
    for (int cc = 0; cc < 4; cc++) {
        float lv[8];
#pragma unroll
        for (int k = 0; k < 8; k++) lv[k] = lp[(size_t)(cc * 8 + k) * (CH * CW)];
#pragma unroll
        for (int o = 0; o < 32; o++)
#pragma unroll
            for (int k = 0; k < 8; k++)
                acc[o] = fmaf(lv[k], w0[o * 66 + cc * 8 + k], acc[o]);
    }
    float4* op = (float4*)(alr + (size_t)idx * 32);
#pragma unroll
    for (int j = 0; j < 8; j++)
        op[j] = make_float4(acc[4 * j], acc[4 * j + 1], acc[4 * j + 2], acc[4 * j + 3]);
}

// Main: one thread per hr pixel; block = 4(h) x 64(w) tile, 256 threads.
// Writes RAW logits (invalid -> -100.0f, the reference pad value); a second
// kernel does the 9-way softmax in-place.
//
// R2-R5 lesson: the allocator insists on ~48-72 VGPRs regardless of
// launch_bounds / amdgpu_waves_per_eu, and spills to *global* scratch
// (WRITE_SIZE 14-19 MB vs 9.4 MB output). So the live set is kept
// structurally under ~48: ahr lives in LDS (manual spill -- the compiler
// cannot spill to LDS), and layers are fused in 8-wide o-chunks so no
// 32-float activation array ever exists.
template <bool USE_WS>
__global__ __launch_bounds__(256) void ercm_main(const float* __restrict__ hr,
                                                 const float* __restrict__ lr,
                                                 const float* __restrict__ alr,
                                                 const float* __restrict__ w0,
                                                 const float* __restrict__ w1,
                                                 const float* __restrict__ w2,
                                                 const float* __restrict__ w3,
                                                 float* __restrict__ out) {
    // s_ahr transposed [o][tid]: addr = (o*256+tid)*4 -> consecutive lanes hit
    // consecutive banks, conflict-free; o-offset folds into ds imm offset.
    __shared__ float s_ahr[32 * 256];          // 32 KB
    // s_alr [cell][c] with stride 33: bank = (cell+c)%32 -> conflict-free on
    // both the staging writes and the per-quad broadcast reads.
    __shared__ float s_alr[54 * 33];           // ~7 KB; total < 40 KB -> 4 blk/CU

    const int tid = threadIdx.x;
    const int bx = blockIdx.x;  // 0..7   (WW/64)
    const int by = blockIdx.y;  // 0..63  (HH/4)
    const int b = blockIdx.z;   // 0..1
    const int cy0 = by, cx0 = bx * 16;

    // ---- stage ALr halo tile (3 x 18 coarse cells) ----
    if (USE_WS) {
        for (int i = tid; i < 54 * 32; i += 256) {
            const int c = i & 31, cell = i >> 5;
            const int row = cell / 18, col = cell - row * 18;
            const int gcy = cy0 - 1 + row, gcx = cx0 - 1 + col;
            float v = 0.f;
            if ((unsigned)gcy < (unsigned)CH && (unsigned)gcx < (unsigned)CW)
                v = alr[(((size_t)b * CH + gcy) * CW + gcx) * 32 + c];
            s_alr[cell * 33 + c] = v;
        }
    } else {
        for (int i = tid; i < 54 * 32; i += 256) {
            const int o = i & 31, cell = i >> 5;
            const int row = cell / 18, col = cell - row * 18;
            const int gcy = cy0 - 1 + row, gcx = cx0 - 1 + col;
            float a = 0.f;
            if ((unsigned)gcy < (unsigned)CH && (unsigned)gcx < (unsigned)CW) {
                const float* lp = lr + (size_t)b * CC * CH * CW + (size_t)gcy * CW + gcx;
#pragma unroll
                for (int c = 0; c < 32; c++) a = fmaf(lp[(size_t)c * (CH * CW)], w0[o * 66 + c], a);
            }
            s_alr[cell * 33 + o] = a;
        }
    }

    const int tx = tid & 63, ty = tid >> 6;
    const int h = by * 4 + ty, w = bx * 64 + tx;
    const size_t HW = (size_t)HH * WW;

    // ---- phase 1: A_hr[o] = sum_c hr[c] * w0[o, 32+c], then park in LDS ----
    {
        float acc[32];
#pragma unroll
        for (int o = 0; o < 32; o++) acc[o] = 0.f;
        const float* hp = hr + (size_t)b * CC * HW + (size_t)h * WW + w;
#pragma unroll
        for (int cc = 0; cc < 4; cc++) {
            float hv[8];
#pragma unroll
            for (int k = 0; k < 8; k++) hv[k] = hp[(size_t)(cc * 8 + k) * HW];
#pragma unroll
            for (int o = 0; o < 32; o++)
#pragma unroll
                for (int k = 0; k < 8; k++)
                    acc[o] = fmaf(hv[k], w0[o * 66 + 32 + cc * 8 + k], acc[o]);
        }
#pragma unroll
        for (int o = 0; o < 32; o++) s_ahr[o * 256 + tid] = acc[o];
    }
    __syncthreads();  // covers s_alr staging (s_ahr is thread-private)

    const int xm = w & 3, ym = h & 3;
    const float xv = (float)(xm < 2 ? xm - 2 : xm - 1);  // x = [-2,-1,1,2]
    const float yv = (float)(ym < 2 ? ym - 2 : ym - 1);
    const float x1 = (float)(4 - xm), x2 = (float)(xm + 1);
    const float y1 = (float)(4 - ym), y2 = (float)(ym + 1);
    const int baseCell = (tx >> 2) + 1;  // local coarse col (+1 halo offset)
    float* op = out + (size_t)b * 9 * HW + (size_t)h * WW + w;

#pragma unroll 1  // rolled: 9x unroll would blow I-cache
    for (int d = 0; d < 9; d++) {
        const int dh = c_dh[d], dw = c_dw[d];
        const int sel0 = c_s0[d], sel1 = c_s1[d];
        const float d0 = (sel0 == 0) ? xv : ((sel0 == 1) ? x1 : x2);
        const float d1 = (sel1 == 0) ? yv : ((sel1 == 1) ? y1 : y2);
        const bool valid = ((unsigned)(h + 4 * dh) < (unsigned)HH) &&
                           ((unsigned)(w + 4 * dw) < (unsigned)WW);
        const int cellBase = ((1 + dh) * 18 + baseCell + dw) * 33;

        // layers 1+2 fused, o-chunked by 8: t[8] live, acc2[16] accumulates.
        // w1 row chunks contiguous -> few s_load_dwordx8 instead of 512
        // scattered s_loads. Accumulation order over o = reference order.
        float acc2[16];
#pragma unroll
        for (int j = 0; j < 16; j++) acc2[j] = 0.f;
#pragma unroll
        for (int oc = 0; oc < 4; oc++) {
            float t[8];
#pragma unroll
            for (int k = 0; k < 8; k++) {
                const int o = oc * 8 + k;
                float v = s_ahr[o * 256 + tid] + s_alr[cellBase + o];
                v = fmaf(d0, w0[o * 66 + 64], v);
                v = fmaf(d1, w0[o * 66 + 65], v);
                t[k] = fmaxf(v, 0.01f * v);
            }
#pragma unroll
            for (int j = 0; j < 16; j++)
#pragma unroll
                for (int k = 0; k < 8; k++)
                    acc2[j] = fmaf(t[k], w1[j * 32 + oc * 8 + k], acc2[j]);
        }
        // layer 3: 16 -> 8, c-chunked by 8 (w2 rows contiguous)
        float h2[8];
#pragma unroll
        for (int o = 0; o < 8; o++) h2[o] = 0.f;
#pragma unroll
        for (int cc = 0; cc < 2; cc++) {
            float t2[8];
#pragma unroll
            for (int k = 0; k < 8; k++) {
                const float a = acc2[cc * 8 + k];
                t2[k] = fmaxf(a, 0.01f * a);
            }
#pragma unroll
            for (int o = 0; o < 8; o++)
#pragma unroll
                for (int k = 0; k < 8; k++)
                    h2[o] = fmaf(t2[k], w2[o * 16 + cc * 8 + k], h2[o]);
        }
        // layer 4: 8 -> 1
        float lg = 0.f;
#pragma unroll
        for (int c = 0; c < 8; c++) {
            const float t = fmaxf(h2[c], 0.01f * h2[c]);
            lg = fmaf(t, w3[c], lg);
        }

        op[(size_t)d * HW] = valid ? lg : -100.0f;  // raw logit
    }
}

// In-place 9-way channel softmax over out[B,9,H,W].
__global__ __launch_bounds__(256) void softmax9(float* __restrict__ out) {
    const int idx = blockIdx.x * 256 + threadIdx.x;  // over BB*HH*WW
    if (idx >= BB * HH * WW) return;
    const size_t HW = (size_t)HH * WW;
    const int b = idx / (HH * WW);
    const int p = idx - b * (HH * WW);
    float* base = out + (size_t)b * 9 * HW + p;
    float l[9];
#pragma unroll
    for (int d = 0; d < 9; d++) l[d] = base[(size_t)d * HW];
    float m = l[0];
#pragma unroll
    for (int d = 1; d < 9; d++) m = fmaxf(m, l[d]);
    float s = 0.f;
#pragma unroll
    for (int d = 0; d < 9; d++) {
        l[d] = __expf(l[d] - m);
        s += l[d];
    }
    const float inv = __builtin_amdgcn_rcpf(s);
#pragma unroll
    for (int d = 0; d < 9; d++) base[(size_t)d * HW] = l[d] * inv;
}

extern "C" void kernel_launch(void* const* d_in, const int* in_sizes, int n_in,
                              void* d_out, int out_size, void* d_ws, size_t ws_size,
                              hipStream_t stream) {
    const float* lr = (const float*)d_in[0];
    const float* hr = (const float*)d_in[1];
    // d_in[2], d_in[3] (lr_feature_r / hr_feature_r) are unused by the reference.
    const float* w0 = (const float*)d_in[4];
    const float* w1 = (const float*)d_in[5];
    const float* w2 = (const float*)d_in[6];
    const float* w3 = (const float*)d_in[7];
    float* out = (float*)d_out;

    const size_t alr_bytes = (size_t)BB * CH * CW * 32 * sizeof(float);  // 2 MB
    dim3 grid(WW / 64, HH / 4, BB);  // 8 x 64 x 2 = 1024 blocks

    if (ws_size >= alr_bytes) {
        float* alr = (float*)d_ws;
        alr_prepass<<<(BB * CH * CW + 255) / 256, 256, 0, stream>>>(lr, w0, alr);
        ercm_main<true><<<grid, 256, 0, stream>>>(hr, lr, alr, w0, w1, w2, w3, out);
    } else {
        ercm_main<false><<<grid, 256, 0, stream>>>(hr, lr, nullptr, w0, w1, w2, w3, out);
    }
    softmax9<<<(BB * HH * WW + 255) / 256, 256, 0, stream>>>(out);
}

// Round 7
// 230.345 us; speedup vs baseline: 3.2867x; 2.7593x over previous
//
#include <hip/hip_runtime.h>
#include <math.h>

#define SC 4
#define BB 2
#define CC 32
#define HH 256
#define WW 512
#define CH (HH / SC)   // 64
#define CW (WW / SC)   // 128

// Direction metadata (output channel order: c, l, r, t, b, lt, rt, lb, rb)
//   s0: 0 -> xv (x[w%4]), 1 -> 4-(w%4) (D1), 2 -> (w%4)+1 (D2)
//   s1: 0 -> yv (x[h%4]), 1 -> 4-(h%4) (D3), 2 -> (h%4)+1 (D4)
// Diagonals reuse D1..D4 which modify ONLY ONE channel each:
//   lt->D1 (ch0=x1, ch1=yv), rt->D2 (ch0=x2, ch1=yv),
//   lb->D3 (ch0=xv, ch1=y1), rb->D4 (ch0=xv, ch1=y2).   [verified R2]
__device__ __constant__ int c_dh[9] = {0, 0, 0, -1, 1, -1, -1, 1, 1};
__device__ __constant__ int c_dw[9] = {0, -1, 1, 0, 0, -1, 1, -1, 1};
__device__ __constant__ int c_s0[9] = {0, 1, 2, 0, 0, 1, 2, 0, 0};
__device__ __constant__ int c_s1[9] = {0, 0, 0, 1, 2, 0, 0, 1, 2};

// Pre-pass: ALr[(b*CH+cy)*CW+cx][o] = sum_c w0[o*66+c] * lr[b][c][cy][cx]
// (R3's exact version -- do not touch, it participates in the good compile.)
__global__ __launch_bounds__(256) void alr_prepass(const float* __restrict__ lr,
                                                   const float* __restrict__ w0,
                                                   float* __restrict__ alr) {
    const int idx = blockIdx.x * 256 + threadIdx.x;  // over BB*CH*CW = 16384
    if (idx >= BB * CH * CW) return;
    const int b = idx / (CH * CW);
    const int cell = idx - b * (CH * CW);
    const float* lp = lr + (size_t)b * CC * CH * CW + cell;
    float lv[32];
#pragma unroll
    for (int c = 0; c < 32; c++) lv[c] = lp[(size_t)c * (CH * CW)];
    float acc[32];
#pragma unroll
    for (int o = 0; o < 32; o++) {
        float a = 0.f;
#pragma unroll
        for (int c = 0; c < 32; c++) a = fmaf(lv[c], w0[o * 66 + c], a);
        acc[o] = a;
    }
    float4* op = (float4*)(alr + (size_t)idx * 32);
#pragma unroll
    for (int j = 0; j < 8; j++)
        op[j] = make_float4(acc[4 * j], acc[4 * j + 1], acc[4 * j + 2], acc[4 * j + 3]);
}

// Main: one thread per hr pixel; block covers a 2(h) x 64(w) tile (128 thr).
//
// R3 (4x64 tile, 256 thr, launch_bounds(256,4)) is the only compile mode
// that produced a lean instruction stream (130us steady; every structural
// rewrite in R4-R6 inflated VALU inst count ~5x at identical source-level
// work). This round keeps the d-loop body BYTE-IDENTICAL to R3 and changes
// exactly one thing: block 256 -> 128 (grid 1024 -> 2048 blocks) to pack
// occupancy toward the 50% structural cap (R3 measured 32%).
template <bool USE_WS>
__global__ __launch_bounds__(128, 4) void ercm_main(const float* __restrict__ hr,
                                                    const float* __restrict__ lr,
                                                    const float* __restrict__ alr,
                                                    const float* __restrict__ w0,
                                                    const float* __restrict__ w1,
                                                    const float* __restrict__ w2,
                                                    const float* __restrict__ w3,
                                                    float* __restrict__ out) {
    // 3 coarse rows x 18 coarse cols of 32-float ALr vectors, padded to 36
    // floats/cell (stride-32 would be a 16-way bank conflict on ds_read_b128;
    // 36 rotates 4 banks/cell -> 2-way broadcast groups, which is free).
    __shared__ float s_alr[54 * 36];
    __shared__ float s_lg[9 * 128];  // per-direction logits (rolled d-loop)

    const int tid = threadIdx.x;
    const int bx = blockIdx.x;  // 0..7    (WW/64)
    const int by = blockIdx.y;  // 0..127  (HH/2)
    const int b = blockIdx.z;   // 0..1
    const int cy0 = by >> 1;    // coarse row of both fine rows in this tile
    const int cx0 = bx * 16;

    if (USE_WS) {
        for (int i = tid; i < 54 * 32; i += 128) {
            const int c = i & 31, cell = i >> 5;
            const int row = cell / 18, col = cell - row * 18;
            const int gcy = cy0 - 1 + row, gcx = cx0 - 1 + col;
            float v = 0.f;
            if ((unsigned)gcy < (unsigned)CH && (unsigned)gcx < (unsigned)CW)
                v = alr[(((size_t)b * CH + gcy) * CW + gcx) * 32 + c];
            s_alr[cell * 36 + c] = v;
        }
    } else {
        // Fallback if workspace too small: compute ALr tile in-block.
        for (int i = tid; i < 54 * 32; i += 128) {
            const int o = i & 31, cell = i >> 5;
            const int row = cell / 18, col = cell - row * 18;
            const int gcy = cy0 - 1 + row, gcx = cx0 - 1 + col;
            float a = 0.f;
            if ((unsigned)gcy < (unsigned)CH && (unsigned)gcx < (unsigned)CW) {
                const float* lp = lr + (size_t)b * CC * CH * CW + (size_t)gcy * CW + gcx;
#pragma unroll
                for (int c = 0; c < 32; c++) a = fmaf(lp[(size_t)c * (CH * CW)], w0[o * 66 + c], a);
            }
            s_alr[cell * 36 + o] = a;
        }
    }
    __syncthreads();

    const int tx = tid & 63, ty = tid >> 6;    // ty in {0,1}
    const int h = by * 2 + ty, w = bx * 64 + tx;
    const size_t HW = (size_t)HH * WW;

    // hr channel vector at the center pixel (shared by all 9 directions)
    float hrv[32];
    const float* hp = hr + (size_t)b * CC * HW + (size_t)h * WW + w;
#pragma unroll
    for (int c = 0; c < 32; c++) hrv[c] = hp[(size_t)c * HW];

    // A_hr[o] = sum_c hr[c] * w0[o, 32+c]  (weights come in as s_loads)
    float ahr[32];
#pragma unroll
    for (int o = 0; o < 32; o++) {
        float a = 0.f;
#pragma unroll
        for (int c = 0; c < 32; c++) a = fmaf(hrv[c], w0[o * 66 + 32 + c], a);
        ahr[o] = a;
    }

    const int xm = w & 3, ym = h & 3;
    const float xv = (float)(xm < 2 ? xm - 2 : xm - 1);  // x = [-2,-1,1,2]
    const float yv = (float)(ym < 2 ? ym - 2 : ym - 1);
    const float x1 = (float)(4 - xm), x2 = (float)(xm + 1);
    const float y1 = (float)(4 - ym), y2 = (float)(ym + 1);
    const int baseCell = (tx >> 2) + 1;  // local coarse col (+1 halo offset)

#pragma unroll 1  // keep rolled: 9x unroll would blow I-cache
    for (int d = 0; d < 9; d++) {
        const int dh = c_dh[d], dw = c_dw[d];
        const int sel0 = c_s0[d], sel1 = c_s1[d];
        const float d0 = (sel0 == 0) ? xv : ((sel0 == 1) ? x1 : x2);
        const float d1 = (sel1 == 0) ? yv : ((sel1 == 1) ? y1 : y2);
        const bool valid = ((unsigned)(h + 4 * dh) < (unsigned)HH) &&
                           ((unsigned)(w + 4 * dw) < (unsigned)WW);

        const float* ap = s_alr + ((1 + dh) * 18 + baseCell + dw) * 36;
        float v[32];
#pragma unroll
        for (int j = 0; j < 8; j++) {
            const float4 q = ((const float4*)ap)[j];
            v[4 * j + 0] = q.x; v[4 * j + 1] = q.y;
            v[4 * j + 2] = q.z; v[4 * j + 3] = q.w;
        }
        // layer 1: A_hr + A_lr + distance part, LeakyReLU(0.01)
#pragma unroll
        for (int o = 0; o < 32; o++) {
            float t = ahr[o] + v[o];
            t = fmaf(d0, w0[o * 66 + 64], t);
            t = fmaf(d1, w0[o * 66 + 65], t);
            v[o] = fmaxf(t, 0.01f * t);
        }
        // layer 2: 32 -> 16
        float h1[16];
#pragma unroll
        for (int o = 0; o < 16; o++) {
            float a = 0.f;
#pragma unroll
            for (int c = 0; c < 32; c++) a = fmaf(v[c], w1[o * 32 + c], a);
            h1[o] = fmaxf(a, 0.01f * a);
        }
        // layer 3: 16 -> 8
        float h2[8];
#pragma unroll
        for (int o = 0; o < 8; o++) {
            float a = 0.f;
#pragma unroll
            for (int c = 0; c < 16; c++) a = fmaf(h1[c], w2[o * 16 + c], a);
            h2[o] = fmaxf(a, 0.01f * a);
        }
        // layer 4: 8 -> 1 (no activation)
        float lg = 0.f;
#pragma unroll
        for (int c = 0; c < 8; c++) lg = fmaf(h2[c], w3[c], lg);

        s_lg[d * 128 + tid] = valid ? lg : -100.0f;
    }

    // softmax over the 9 direction logits
    float l[9];
#pragma unroll
    for (int d = 0; d < 9; d++) l[d] = s_lg[d * 128 + tid];
    float m = l[0];
#pragma unroll
    for (int d = 1; d < 9; d++) m = fmaxf(m, l[d]);
    float s = 0.f;
#pragma unroll
    for (int d = 0; d < 9; d++) {
        l[d] = __expf(l[d] - m);
        s += l[d];
    }
    const float inv = __builtin_amdgcn_rcpf(s);
    float* op = out + (size_t)b * 9 * HW + (size_t)h * WW + w;
#pragma unroll
    for (int d = 0; d < 9; d++) op[(size_t)d * HW] = l[d] * inv;
}

extern "C" void kernel_launch(void* const* d_in, const int* in_sizes, int n_in,
                              void* d_out, int out_size, void* d_ws, size_t ws_size,
                              hipStream_t stream) {
    const float* lr = (const float*)d_in[0];
    const float* hr = (const float*)d_in[1];
    // d_in[2], d_in[3] (lr_feature_r / hr_feature_r) are unused by the reference.
    const float* w0 = (const float*)d_in[4];
    const float* w1 = (const float*)d_in[5];
    const float* w2 = (const float*)d_in[6];
    const float* w3 = (const float*)d_in[7];
    float* out = (float*)d_out;

    const size_t alr_bytes = (size_t)BB * CH * CW * 32 * sizeof(float);  // 2 MB
    dim3 grid(WW / 64, HH / 2, BB);  // 8 x 128 x 2 = 2048 blocks of 128 thr

    if (ws_size >= alr_bytes) {
        float* alr = (float*)d_ws;
        alr_prepass<<<(BB * CH * CW + 255) / 256, 256, 0, stream>>>(lr, w0, alr);
        ercm_main<true><<<grid, 128, 0, stream>>>(hr, lr, alr, w0, w1, w2, w3, out);
    } else {
        ercm_main<false><<<grid, 128, 0, stream>>>(hr, lr, nullptr, w0, w1, w2, w3, out);
    }
}